// Round 3
// baseline (256.596 us; speedup 1.0000x reference)
//
#include <hip/hip_runtime.h>
#include <stdint.h>

// FFM: B=4096, F=20 fields x S=500 feats, K=16.
// E[b,g,i,k] = sum_s x[b,i*500+s] * v[g,i*500+s,k]   (20 GEMMs [B,500]x[500,320])
// out[b] = x[b,:]@w + sum_{i<j} sum_k E[b,j,i,k]*E[b,i,j,k]

#define NF 20
#define FS 500
#define TFEAT 10000
#define KD 16
#define NC 320          // NF*KD, GEMM N
#define KP 512          // K padded to mult of 64
#define NB 4096

typedef __bf16 bf16x8 __attribute__((ext_vector_type(8)));
typedef __bf16 bf16x4 __attribute__((ext_vector_type(4)));
typedef __bf16 bf16x2 __attribute__((ext_vector_type(2)));
typedef float  f32x4  __attribute__((ext_vector_type(4)));
typedef unsigned int u32x4 __attribute__((ext_vector_type(4)));

typedef __attribute__((address_space(1))) const void* as1cv;
typedef __attribute__((address_space(3))) void* as3v;

__device__ inline void gload_lds16(const void* g, void* l) {
  __builtin_amdgcn_global_load_lds((as1cv)g, (as3v)l, 16, 0, 0);
}

// ---------------- prep: Vt[i][n][kk] = v[g, i*500+kk, k], n=g*16+k, kk<512 (0-padded)
__global__ __launch_bounds__(256) void prep_vt(const float* __restrict__ v,
                                               __bf16* __restrict__ Vt) {
  __shared__ float lv[FS * 17];
  const int i = blockIdx.x / NF;
  const int g = blockIdx.x % NF;
  const int t = threadIdx.x;
  const int k = t & 15, sb = t >> 4;
  const float* vb = v + ((size_t)g * TFEAT + (size_t)i * FS) * KD;
  for (int it = 0; it < 32; ++it) {
    int s = it * 16 + sb;
    if (s < FS) lv[s * 17 + k] = vb[(size_t)s * KD + k];
  }
  __syncthreads();
  __bf16* out = Vt + ((size_t)(i * NC + g * 16)) * KP;
  for (int r = 0; r < 16; ++r) {
    int s0 = 2 * t, s1 = 2 * t + 1;
    bf16x2 pr;
    pr[0] = (s0 < FS) ? (__bf16)lv[s0 * 17 + r] : (__bf16)0.f;
    pr[1] = (s1 < FS) ? (__bf16)lv[s1 * 17 + r] : (__bf16)0.f;
    *(bf16x2*)(out + (size_t)r * KP + 2 * t) = pr;
  }
}

// ---------------- K1: per-field GEMM + fused linear partial
// grid = NF * tiles * 2 (N halves), block 256 = 4 waves (2M x 2N).
// BM=128, BN=160, BK=64. Wave tile 64x80 -> acc[4][5].
// Both operands double-buffered; loads issued at TOP of iter (full phase to land);
// ONE vmcnt(0)+lgkmcnt(0)+s_barrier per iter (2-phase recipe, T3-minimal).
__global__ __launch_bounds__(256, 2) void k1_gemm(
    const float* __restrict__ x, const float* __restrict__ w,
    const __bf16* __restrict__ Vt, __bf16* __restrict__ E,
    float* __restrict__ lin, int chunk_base, int tiles) {
  __shared__ __align__(16) __bf16 As[2][128][72];   // 36.9 KB
  __shared__ __align__(16) __bf16 Bs[2][160 * 64];  // 40 KB, 16B-chunk XOR-swizzled

  const int bx = blockIdx.x;
  const int ns = bx & 1;            // N half (0/1)
  const int bf_ = bx >> 1;
  const int i  = bf_ / tiles;       // field
  const int tb = bf_ % tiles;       // batch tile
  const int tid = threadIdx.x;
  const int lane = tid & 63, wid = tid >> 6;
  const int wm = wid >> 1, wn = wid & 1;

  const int b0 = chunk_base + tb * 128;
  const int rblk = tid >> 2;                     // 0..63; rows rblk, rblk+64
  const int c0 = (tid & 3) * 16;                 // 16 f32 cols per thread
  const float* xrow0 = x + (size_t)(b0 + rblk) * TFEAT + i * FS;
  const float* xrow1 = xrow0 + (size_t)64 * TFEAT;
  const float* wcol = w + i * FS;

  // B staging: wave stages rows [wid*40, wid*40+40) in 5 glds (8 rows x 8 chunks each)
  const int lrow = lane >> 3;
  const int lswz = ((lane & 7) ^ lrow) * 8;      // pre-swizzled src k-offset (elems)
  const __bf16* VtB = Vt + ((size_t)i * NC + ns * 160) * KP;

  float lp0 = 0.f, lp1 = 0.f;
  f32x4 acc[4][5];
#pragma unroll
  for (int m = 0; m < 4; ++m)
#pragma unroll
    for (int nf = 0; nf < 5; ++nf) acc[m][nf] = (f32x4){0.f, 0.f, 0.f, 0.f};
  f32x4 ar0[4], ar1[4];

  auto issueB = [&](int t, int buf) {
#pragma unroll
    for (int jj = 0; jj < 5; ++jj) {
      int n = wid * 40 + jj * 8 + lrow;
      gload_lds16(VtB + (size_t)n * KP + t * 64 + lswz,
                  (void*)(&Bs[buf][(wid * 40 + jj * 8) * 64]));
    }
  };
  auto loadA = [&](int t) {
#pragma unroll
    for (int j = 0; j < 4; ++j) {
      int c = t * 64 + c0 + j * 4;
      bool ok = c < FS;
      ar0[j] = ok ? *(const f32x4*)(xrow0 + c) : (f32x4){0.f, 0.f, 0.f, 0.f};
      ar1[j] = ok ? *(const f32x4*)(xrow1 + c) : (f32x4){0.f, 0.f, 0.f, 0.f};
    }
  };
  auto storeA = [&](int t, int buf) {
#pragma unroll
    for (int j = 0; j < 4; ++j) {
      int c = t * 64 + c0 + j * 4;
      if (c < FS) {
        f32x4 wv = *(const f32x4*)(wcol + c);
        lp0 += ar0[j][0] * wv[0] + ar0[j][1] * wv[1] + ar0[j][2] * wv[2] + ar0[j][3] * wv[3];
        lp1 += ar1[j][0] * wv[0] + ar1[j][1] * wv[1] + ar1[j][2] * wv[2] + ar1[j][3] * wv[3];
      }
    }
#pragma unroll
    for (int h = 0; h < 2; ++h) {
      bf16x8 p0, p1;
#pragma unroll
      for (int e = 0; e < 4; ++e) {
        p0[e] = (__bf16)ar0[h * 2][e];     p0[4 + e] = (__bf16)ar0[h * 2 + 1][e];
        p1[e] = (__bf16)ar1[h * 2][e];     p1[4 + e] = (__bf16)ar1[h * 2 + 1][e];
      }
      *(bf16x8*)(&As[buf][rblk][c0 + h * 8]) = p0;
      *(bf16x8*)(&As[buf][rblk + 64][c0 + h * 8]) = p1;
    }
  };

  // prologue: stage tile 0 into buf 0
  issueB(0, 0);
  loadA(0);
  storeA(0, 0);
  asm volatile("s_waitcnt vmcnt(0) lgkmcnt(0)" ::: "memory");
  __builtin_amdgcn_s_barrier();

  for (int t = 0; t < 8; ++t) {
    const int cur = t & 1;
    if (t < 7) {                       // issue next tile's loads FIRST (full phase to land)
      issueB(t + 1, cur ^ 1);
      loadA(t + 1);
    }
    __builtin_amdgcn_sched_barrier(0); // pin issues before compute
#pragma unroll
    for (int ks = 0; ks < 2; ++ks) {
      bf16x8 af[4];
#pragma unroll
      for (int m = 0; m < 4; ++m)
        af[m] = *(const bf16x8*)(&As[cur][wm * 64 + m * 16 + (lane & 15)][ks * 32 + (lane >> 4) * 8]);
#pragma unroll
      for (int nf = 0; nf < 5; ++nf) {
        int n = wn * 80 + nf * 16 + (lane & 15);
        int pc = (ks * 4 + (lane >> 4)) ^ (n & 7);
        bf16x8 bfr = *(const bf16x8*)(&Bs[cur][n * 64 + pc * 8]);
#pragma unroll
        for (int m = 0; m < 4; ++m)
          acc[m][nf] = __builtin_amdgcn_mfma_f32_16x16x32_bf16(af[m], bfr, acc[m][nf], 0, 0, 0);
      }
    }
    if (t < 7) {
      storeA(t + 1, cur ^ 1);          // cvt auto-waits its A vmcnt; writes other buffer
      asm volatile("s_waitcnt vmcnt(0) lgkmcnt(0)" ::: "memory");
      __builtin_amdgcn_s_barrier();    // single barrier per iter
    }
  }

  // linear partial (N-half 0 only, to avoid double count)
  if (ns == 0) {
    lp0 += __shfl_xor(lp0, 1); lp0 += __shfl_xor(lp0, 2);
    lp1 += __shfl_xor(lp1, 1); lp1 += __shfl_xor(lp1, 2);
    if ((lane & 3) == 0) {
      atomicAdd(&lin[b0 + rblk], lp0);
      atomicAdd(&lin[b0 + rblk + 64], lp1);
    }
  }

  // epilogue: E[b_local][i*320+n], C/D layout col=lane&15, row=(lane>>4)*4+r
  const int lrow4 = (lane >> 4) * 4, lcol = lane & 15;
#pragma unroll
  for (int m = 0; m < 4; ++m)
#pragma unroll
    for (int nf = 0; nf < 5; ++nf) {
      int n = ns * 160 + wn * 80 + nf * 16 + lcol;
#pragma unroll
      for (int r = 0; r < 4; ++r) {
        int bl = tb * 128 + wm * 64 + m * 16 + lrow4 + r;
        E[(size_t)bl * (NF * NC) + i * NC + n] = (__bf16)acc[m][nf][r];
      }
    }
}

// ---------------- K2: pair reduction, 1 wave per batch row
__global__ __launch_bounds__(256) void k2_pair(
    const __bf16* __restrict__ E, const float* __restrict__ lin,
    float* __restrict__ out, int chunk_base) {
  __shared__ __align__(16) unsigned shw[4][3200];
  const int tid = threadIdx.x, lane = tid & 63, wid = tid >> 6;
  const int bl = blockIdx.x * 4 + wid;
  const unsigned* src = (const unsigned*)(E + (size_t)bl * (NF * NC));
  for (int it = 0; it < 13; ++it) {
    int idx = it * 64 + lane;
    if (idx < 800) {
      u32x4 val = *(const u32x4*)(src + (size_t)idx * 4);
      *(u32x4*)&shw[wid][idx * 4] = val;
    }
  }
  __syncthreads();
  const __bf16* sh = (const __bf16*)shw[wid];
  const int k = lane & 15, g = lane >> 4;
  float sum = 0.f;
  for (int i = g; i < NF; i += 4)
    for (int j = i + 1; j < NF; ++j)
      sum += (float)sh[i * NC + j * 16 + k] * (float)sh[j * NC + i * 16 + k];
#pragma unroll
  for (int off = 32; off; off >>= 1) sum += __shfl_xor(sum, off);
  if (lane == 0) {
    int bg = chunk_base + bl;
    out[bg] = lin[bg] + sum;
  }
}

extern "C" void kernel_launch(void* const* d_in, const int* in_sizes, int n_in,
                              void* d_out, int out_size, void* d_ws, size_t ws_size,
                              hipStream_t stream) {
  const float* x = (const float*)d_in[0];
  const float* w = (const float*)d_in[1];
  const float* v = (const float*)d_in[2];
  float* out = (float*)d_out;
  char* ws = (char*)d_ws;

  __bf16* Vt = (__bf16*)ws;                                // 6,553,600 B
  float* lin = (float*)(ws + 6553600);                     // 16,384 B
  __bf16* E  = (__bf16*)(ws + 6553600 + 16384);            // Bc*6400*2 B

  size_t eavail = (ws_size > 6569984) ? ws_size - 6569984 : 0;
  int Bc = NB;
  while (Bc > 128 && (size_t)Bc * (NF * NC) * 2 > eavail) Bc >>= 1;

  hipMemsetAsync(lin, 0, NB * sizeof(float), stream);
  prep_vt<<<NF * NF, 256, 0, stream>>>(v, Vt);
  for (int cb = 0; cb < NB; cb += Bc) {
    int tiles = Bc / 128;
    k1_gemm<<<NF * tiles * 2, 256, 0, stream>>>(x, w, Vt, E, lin, cb, tiles);
    k2_pair<<<Bc / 4, 256, 0, stream>>>(E, lin, out, cb);
  }
}

// Round 4
// 90.991 us; speedup vs baseline: 2.8200x; 2.8200x over previous
//
#include <hip/hip_runtime.h>
#include <stdint.h>

// FFM: B=4096, F=20 fields x S=500 feats, K=16.
// E2[b, i*336 + g*16 + k] = sum_s x[b,i*500+s]*v[g,i*500+s,k]  (g<20)
// E2[b, i*336 + 320]      = sum_s x[b,i*500+s]*w[i*500+s]      (linear partial)
// out[b] = sum_i E2[b,i,320] + sum_{i<j,k} E2[b,i*336+j*16+k]*E2[b,j*336+i*16+k]

#define NF 20
#define FS 500
#define TFEAT 10000
#define KD 16
#define NCOL 336        // 21 frags: 320 interaction cols + 16-col w block
#define NFRG 21
#define KP 512
#define NB 4096
#define ROWE (NF * NCOL)  // 6720

typedef __bf16 bf16x8 __attribute__((ext_vector_type(8)));
typedef __bf16 bf16x2 __attribute__((ext_vector_type(2)));
typedef float  f32x4  __attribute__((ext_vector_type(4)));
typedef unsigned int u32x4 __attribute__((ext_vector_type(4)));

typedef __attribute__((address_space(1))) const void* as1cv;
typedef __attribute__((address_space(3))) void* as3v;

__device__ inline void gload_lds16(const void* g, void* l) {
  __builtin_amdgcn_global_load_lds((as1cv)g, (as3v)l, 16, 0, 0);
}

// ---------------- prep: Vt[i][n][kk], n<336: n=g*16+k -> v[g,i*500+kk,k]; n=320 -> w; rest 0
__global__ __launch_bounds__(256) void prep_vt(const float* __restrict__ v,
                                               const float* __restrict__ w,
                                               __bf16* __restrict__ Vt) {
  const int i = blockIdx.x / (NF + 1);
  const int g = blockIdx.x % (NF + 1);
  const int t = threadIdx.x;
  if (g == NF) {  // w block: rows 320..335
    const float* wf = w + (size_t)i * FS;
    __bf16* o = Vt + ((size_t)i * NCOL + 320) * KP;
    for (int idx = t; idx < 16 * KP; idx += 256) {
      int r = idx >> 9, kk = idx & (KP - 1);
      __bf16 val = (__bf16)0.f;
      if (r == 0 && kk < FS) val = (__bf16)wf[kk];
      o[(size_t)r * KP + kk] = val;
    }
    return;
  }
  __shared__ float lv[FS * 17];
  const int k = t & 15, sb = t >> 4;
  const float* vb = v + ((size_t)g * TFEAT + (size_t)i * FS) * KD;
  for (int it = 0; it < 32; ++it) {
    int s = it * 16 + sb;
    if (s < FS) lv[s * 17 + k] = vb[(size_t)s * KD + k];
  }
  __syncthreads();
  __bf16* out = Vt + ((size_t)i * NCOL + g * 16) * KP;
  for (int r = 0; r < 16; ++r) {
    int s0 = 2 * t, s1 = 2 * t + 1;
    bf16x2 pr;
    pr[0] = (s0 < FS) ? (__bf16)lv[s0 * 17 + r] : (__bf16)0.f;
    pr[1] = (s1 < FS) ? (__bf16)lv[s1 * 17 + r] : (__bf16)0.f;
    *(bf16x2*)(out + (size_t)r * KP + 2 * t) = pr;
  }
}

// ---------------- K1: per-field GEMM, m230 2-phase. BM=64, BN=336, BK=32, 16 steps.
// A staged as F32 via global_load_lds (XOR-swizzled source, cvt at consume).
// B staged bf16 via global_load_lds (XOR-swizzled source). One vmcnt(0)+barrier/iter.
__global__ __launch_bounds__(256, 2) void k1_gemm(
    const float* __restrict__ x, const __bf16* __restrict__ Vt,
    __bf16* __restrict__ E2, int chunk_base, int tiles) {
  __shared__ float  Af[2][64][32];        // 16384 B, chunk p = c ^ (row&7)
  __shared__ __bf16 Bs[2][NCOL * 32];     // 43008 B, chunk p = c ^ ((n>>1)&3)

  const int bx = blockIdx.x;
  const int i  = bx / tiles;
  const int tb = bx % tiles;
  const int tid = threadIdx.x;
  const int lane = tid & 63, wid = tid >> 6;
  const int b0 = chunk_base + tb * 64;

  // A stage: 2 instrs/wave, 8 rows x 8 chunks each; src col pre-swizzled
  const int arow_off = lane >> 3;                   // 0..7
  const int alc4 = ((lane & 7) ^ arow_off) * 4;     // logical f32 col within step
  const float* xA0 = x + (size_t)(b0 + 16 * wid + arow_off) * TFEAT + i * FS;
  const float* xA1 = xA0 + (size_t)8 * TFEAT;
  // B stage: instr q covers 16 rows x 4 chunks; src chunk pre-swizzled
  const int brow_off = lane >> 2;                   // 0..15
  const int blc8 = ((lane & 3) ^ ((lane >> 3) & 3)) * 8;
  const __bf16* VtB = Vt + (size_t)i * NCOL * KP;

  auto stage = [&](int t, int buf) {
    int soffA = t * 32 + alc4;
    if (soffA > FS - 4) soffA = FS - 4;   // clamp (garbage cols x zero B rows)
    gload_lds16(xA0 + soffA, (void*)&Af[buf][16 * wid][0]);
    gload_lds16(xA1 + soffA, (void*)&Af[buf][16 * wid + 8][0]);
    int soffB = t * 32 + blc8;
#pragma unroll
    for (int jj = 0; jj < 6; ++jj) {
      int q = wid + 4 * jj;
      if (q < NFRG)
        gload_lds16(VtB + (size_t)(16 * q + brow_off) * KP + soffB,
                    (void*)&Bs[buf][q * 16 * 32]);
    }
  };

  const int nfr = wid ? 5 : 6;
  const int Fbase = wid ? (1 + wid * 5) : 0;
  const int ar = lane & 15, ar7 = lane & 7, aq2 = (lane >> 4) * 2;

  f32x4 acc[4][6];
#pragma unroll
  for (int m = 0; m < 4; ++m)
#pragma unroll
    for (int nf = 0; nf < 6; ++nf) acc[m][nf] = (f32x4){0.f, 0.f, 0.f, 0.f};

  stage(0, 0);
  asm volatile("s_waitcnt vmcnt(0)" ::: "memory");
  __builtin_amdgcn_s_barrier();

  for (int t = 0; t < 16; ++t) {
    const int cur = t & 1;
    if (t < 15) stage(t + 1, cur ^ 1);     // pure issue, no data dependency
    __builtin_amdgcn_sched_barrier(0);

    bf16x8 bfr[6];
#pragma unroll
    for (int nf = 0; nf < 6; ++nf)
      if (nf < nfr) {
        int n_ = (Fbase + nf) * 16 + ar;
        int pc = (lane >> 4) ^ ((n_ >> 1) & 3);
        bfr[nf] = *(const bf16x8*)&Bs[cur][n_ * 32 + pc * 8];
      }
#pragma unroll
    for (int m = 0; m < 4; ++m) {
      const float* ap = &Af[cur][m * 16 + ar][0];
      f32x4 u0 = *(const f32x4*)(ap + (aq2 ^ ar7) * 4);
      f32x4 u1 = *(const f32x4*)(ap + ((aq2 + 1) ^ ar7) * 4);
      bf16x8 af;
      af[0] = (__bf16)u0[0]; af[1] = (__bf16)u0[1];
      af[2] = (__bf16)u0[2]; af[3] = (__bf16)u0[3];
      af[4] = (__bf16)u1[0]; af[5] = (__bf16)u1[1];
      af[6] = (__bf16)u1[2]; af[7] = (__bf16)u1[3];
#pragma unroll
      for (int nf = 0; nf < 6; ++nf)
        if (nf < nfr)
          acc[m][nf] = __builtin_amdgcn_mfma_f32_16x16x32_bf16(af, bfr[nf],
                                                               acc[m][nf], 0, 0, 0);
    }
    if (t < 15) {
      asm volatile("s_waitcnt vmcnt(0)" ::: "memory");
      __builtin_amdgcn_s_barrier();
    }
  }

  // epilogue: C/D layout col=lane&15, row=(lane>>4)*4+r
  const int lr4 = (lane >> 4) * 4, lcol = lane & 15;
#pragma unroll
  for (int m = 0; m < 4; ++m)
#pragma unroll
    for (int nf = 0; nf < 6; ++nf)
      if (nf < nfr) {
        int n = (Fbase + nf) * 16 + lcol;
#pragma unroll
        for (int r = 0; r < 4; ++r) {
          int bl = tb * 64 + m * 16 + lr4 + r;
          E2[(size_t)bl * ROWE + i * NCOL + n] = (__bf16)acc[m][nf][r];
        }
      }
}

// ---------------- K2: pair + linear reduction, 1 wave per batch row
__global__ __launch_bounds__(256) void k2_pair(
    const __bf16* __restrict__ E2, float* __restrict__ out, int chunk_base) {
  __shared__ __align__(16) unsigned shw[4][3360];  // 13440 B per wave
  const int tid = threadIdx.x, lane = tid & 63, wid = tid >> 6;
  const int bl = blockIdx.x * 4 + wid;
  const unsigned* src = (const unsigned*)(E2 + (size_t)bl * ROWE);
  for (int it = 0; it < 14; ++it) {
    int idx = it * 64 + lane;             // 16B units; 840 total
    if (idx < 840) {
      u32x4 val = *(const u32x4*)(src + (size_t)idx * 4);
      *(u32x4*)&shw[wid][idx * 4] = val;
    }
  }
  __syncthreads();
  const __bf16* sh = (const __bf16*)shw[wid];
  const int k = lane & 15, g = lane >> 4;
  float sum = 0.f;
  for (int i = g; i < NF; i += 4)
    for (int j = i + 1; j < NF; ++j)
      sum += (float)sh[i * NCOL + j * 16 + k] * (float)sh[j * NCOL + i * 16 + k];
  if (lane < NF) sum += (float)sh[lane * NCOL + 320];   // linear term
#pragma unroll
  for (int off = 32; off; off >>= 1) sum += __shfl_xor(sum, off);
  if (lane == 0) out[chunk_base + bl] = sum;
}

extern "C" void kernel_launch(void* const* d_in, const int* in_sizes, int n_in,
                              void* d_out, int out_size, void* d_ws, size_t ws_size,
                              hipStream_t stream) {
  const float* x = (const float*)d_in[0];
  const float* w = (const float*)d_in[1];
  const float* v = (const float*)d_in[2];
  float* out = (float*)d_out;
  char* ws = (char*)d_ws;

  const size_t vt_bytes = (size_t)NF * NCOL * KP * 2;   // 6,881,280
  __bf16* Vt = (__bf16*)ws;
  __bf16* E2 = (__bf16*)(ws + vt_bytes);

  size_t eavail = (ws_size > vt_bytes) ? ws_size - vt_bytes : 0;
  int Bc = NB;
  while (Bc > 64 && (size_t)Bc * ROWE * 2 > eavail) Bc >>= 1;

  prep_vt<<<NF * (NF + 1), 256, 0, stream>>>(v, w, Vt);
  for (int cb = 0; cb < NB; cb += Bc) {
    int tiles = Bc / 64;
    k1_gemm<<<NF * tiles, 256, 0, stream>>>(x, Vt, E2, cb, tiles);
    k2_pair<<<Bc / 4, 256, 0, stream>>>(E2, out, cb);
  }
}

// Round 5
// 90.100 us; speedup vs baseline: 2.8479x; 1.0099x over previous
//
#include <hip/hip_runtime.h>
#include <stdint.h>

// FFM: B=4096, F=20 fields x S=500 feats, K=16.
// E2[b, i*336 + g*16 + k] = sum_s x[b,i*500+s]*v[g,i*500+s,k]  (g<20)
// E2[b, i*336 + 320]      = sum_s x[b,i*500+s]*w[i*500+s]      (linear partial)
// out[b] = sum_i E2[b,i,320] + sum_{i<j,k} E2[b,i*336+j*16+k]*E2[b,j*336+i*16+k]

#define NF 20
#define FS 500
#define TFEAT 10000
#define KD 16
#define NCOL 336        // 21 frags: 320 interaction cols + 16-col w block
#define NFRG 21
#define KP 512
#define NB 4096
#define ROWE (NF * NCOL)  // 6720

typedef __bf16 bf16x8 __attribute__((ext_vector_type(8)));
typedef __bf16 bf16x2 __attribute__((ext_vector_type(2)));
typedef float  f32x4  __attribute__((ext_vector_type(4)));
typedef unsigned int u32x4 __attribute__((ext_vector_type(4)));

typedef __attribute__((address_space(1))) const void* as1cv;
typedef __attribute__((address_space(3))) void* as3v;

__device__ inline void gload_lds16(const void* g, void* l) {
  __builtin_amdgcn_global_load_lds((as1cv)g, (as3v)l, 16, 0, 0);
}

// ---------------- prep: Vt[i][n][kk], n<336: n=g*16+k -> v[g,i*500+kk,k]; n=320 -> w; rest 0
__global__ __launch_bounds__(256) void prep_vt(const float* __restrict__ v,
                                               const float* __restrict__ w,
                                               __bf16* __restrict__ Vt) {
  const int i = blockIdx.x / (NF + 1);
  const int g = blockIdx.x % (NF + 1);
  const int t = threadIdx.x;
  if (g == NF) {  // w block: rows 320..335
    const float* wf = w + (size_t)i * FS;
    __bf16* o = Vt + ((size_t)i * NCOL + 320) * KP;
    for (int idx = t; idx < 16 * KP; idx += 256) {
      int r = idx >> 9, kk = idx & (KP - 1);
      __bf16 val = (__bf16)0.f;
      if (r == 0 && kk < FS) val = (__bf16)wf[kk];
      o[(size_t)r * KP + kk] = val;
    }
    return;
  }
  __shared__ float lv[FS * 17];
  const int k = t & 15, sb = t >> 4;
  const float* vb = v + ((size_t)g * TFEAT + (size_t)i * FS) * KD;
  for (int it = 0; it < 32; ++it) {
    int s = it * 16 + sb;
    if (s < FS) lv[s * 17 + k] = vb[(size_t)s * KD + k];
  }
  __syncthreads();
  __bf16* out = Vt + ((size_t)i * NCOL + g * 16) * KP;
  for (int r = 0; r < 16; ++r) {
    int s0 = 2 * t, s1 = 2 * t + 1;
    bf16x2 pr;
    pr[0] = (s0 < FS) ? (__bf16)lv[s0 * 17 + r] : (__bf16)0.f;
    pr[1] = (s1 < FS) ? (__bf16)lv[s1 * 17 + r] : (__bf16)0.f;
    *(bf16x2*)(out + (size_t)r * KP + 2 * t) = pr;
  }
}

// ---------------- K1: per-field GEMM. BM=64, BN=336, BK=32, 16 steps.
// A: f32 via global_load_lds, TRIPLE-buffered, issued 2 steps ahead (HBM latency).
// B: bf16 via global_load_lds, double-buffered, issued 1 step ahead (L2 latency).
// Per-iter: issue B(t+1), issue A(t+2), compute(t), s_waitcnt vmcnt(2) (counted!,
// leaves A(t+2) in flight), s_barrier. vmcnt never drains to 0 in steady state.
__global__ __launch_bounds__(256, 2) void k1_gemm(
    const float* __restrict__ x, const __bf16* __restrict__ Vt,
    __bf16* __restrict__ E2, int chunk_base, int tiles) {
  __shared__ float  Af[3][64][32];        // 24576 B, chunk p = c ^ (row&7)
  __shared__ __bf16 Bs[2][NCOL * 32];     // 43008 B, chunk p = c ^ ((n>>1)&3)

  const int bx = blockIdx.x;
  const int i  = bx / tiles;
  const int tb = bx % tiles;
  const int tid = threadIdx.x;
  const int lane = tid & 63, wid = tid >> 6;
  const int b0 = chunk_base + tb * 64;

  // A stage: 2 instrs/wave, 8 rows x 8 chunks each; src col pre-swizzled
  const int arow_off = lane >> 3;                   // 0..7
  const int alc4 = ((lane & 7) ^ arow_off) * 4;     // logical f32 col within step
  const float* xA0 = x + (size_t)(b0 + 16 * wid + arow_off) * TFEAT + i * FS;
  const float* xA1 = xA0 + (size_t)8 * TFEAT;
  // B stage: instr q covers 16 rows x 4 chunks; src chunk pre-swizzled
  const int brow_off = lane >> 2;                   // 0..15
  const int blc8 = ((lane & 3) ^ ((lane >> 3) & 3)) * 8;
  const __bf16* VtB = Vt + (size_t)i * NCOL * KP;

  auto issueB = [&](int t, int buf) {
    int soffB = t * 32 + blc8;
#pragma unroll
    for (int jj = 0; jj < 6; ++jj) {
      int q = wid + 4 * jj;
      if (q < NFRG)
        gload_lds16(VtB + (size_t)(16 * q + brow_off) * KP + soffB,
                    (void*)&Bs[buf][q * 16 * 32]);
    }
  };
  auto issueA = [&](int t, int buf) {
    int soffA = t * 32 + alc4;
    if (soffA > FS - 4) soffA = FS - 4;   // clamp (garbage cols pair with zero B rows)
    gload_lds16(xA0 + soffA, (void*)&Af[buf][16 * wid][0]);
    gload_lds16(xA1 + soffA, (void*)&Af[buf][16 * wid + 8][0]);
  };

  const int nfr = wid ? 5 : 6;
  const int Fbase = wid ? (1 + wid * 5) : 0;
  const int ar = lane & 15, ar7 = lane & 7, aq2 = (lane >> 4) * 2;

  f32x4 acc[4][6];
#pragma unroll
  for (int m = 0; m < 4; ++m)
#pragma unroll
    for (int nf = 0; nf < 6; ++nf) acc[m][nf] = (f32x4){0.f, 0.f, 0.f, 0.f};

  // prologue: B(0), A(0) drained; A(1) left in flight
  issueB(0, 0);
  issueA(0, 0);
  issueA(1, 1);
  asm volatile("s_waitcnt vmcnt(2)" ::: "memory");
  __builtin_amdgcn_s_barrier();

#pragma unroll
  for (int t = 0; t < 16; ++t) {
    const int cur = t & 1;
    const int ab = t % 3;
    if (t < 15) issueB(t + 1, cur ^ 1);          // oldest of this iter's issues
    if (t < 14) issueA(t + 2, (t + 2) % 3);      // newest: stays in flight at drain
    __builtin_amdgcn_sched_barrier(0);

    bf16x8 bfr[6];
#pragma unroll
    for (int nf = 0; nf < 6; ++nf)
      if (nf < nfr) {
        int n_ = (Fbase + nf) * 16 + ar;
        int pc = (lane >> 4) ^ ((n_ >> 1) & 3);
        bfr[nf] = *(const bf16x8*)&Bs[cur][n_ * 32 + pc * 8];
      }
#pragma unroll
    for (int m = 0; m < 4; ++m) {
      const float* ap = &Af[ab][m * 16 + ar][0];
      f32x4 u0 = *(const f32x4*)(ap + (aq2 ^ ar7) * 4);
      f32x4 u1 = *(const f32x4*)(ap + ((aq2 + 1) ^ ar7) * 4);
      bf16x8 af;
      af[0] = (__bf16)u0[0]; af[1] = (__bf16)u0[1];
      af[2] = (__bf16)u0[2]; af[3] = (__bf16)u0[3];
      af[4] = (__bf16)u1[0]; af[5] = (__bf16)u1[1];
      af[6] = (__bf16)u1[2]; af[7] = (__bf16)u1[3];
#pragma unroll
      for (int nf = 0; nf < 6; ++nf)
        if (nf < nfr)
          acc[m][nf] = __builtin_amdgcn_mfma_f32_16x16x32_bf16(af, bfr[nf],
                                                               acc[m][nf], 0, 0, 0);
    }
    if (t < 15) {
      if (t < 14) {
        asm volatile("s_waitcnt vmcnt(2)" ::: "memory");  // counted: A(t+2) stays out
      } else {
        asm volatile("s_waitcnt vmcnt(0)" ::: "memory");  // tail: nothing ahead
      }
      __builtin_amdgcn_s_barrier();
    }
  }

  // epilogue: C/D layout col=lane&15, row=(lane>>4)*4+r
  const int lr4 = (lane >> 4) * 4, lcol = lane & 15;
#pragma unroll
  for (int m = 0; m < 4; ++m)
#pragma unroll
    for (int nf = 0; nf < 6; ++nf)
      if (nf < nfr) {
        int n = (Fbase + nf) * 16 + lcol;
#pragma unroll
        for (int r = 0; r < 4; ++r) {
          int bl = tb * 64 + m * 16 + lr4 + r;
          E2[(size_t)bl * ROWE + i * NCOL + n] = (__bf16)acc[m][nf][r];
        }
      }
}

// ---------------- K2: pair + linear reduction, 1 wave per batch row
__global__ __launch_bounds__(256) void k2_pair(
    const __bf16* __restrict__ E2, float* __restrict__ out, int chunk_base) {
  __shared__ __align__(16) unsigned shw[4][3360];  // 13440 B per wave
  const int tid = threadIdx.x, lane = tid & 63, wid = tid >> 6;
  const int bl = blockIdx.x * 4 + wid;
  const unsigned* src = (const unsigned*)(E2 + (size_t)bl * ROWE);
  for (int it = 0; it < 14; ++it) {
    int idx = it * 64 + lane;             // 16B units; 840 total
    if (idx < 840) {
      u32x4 val = *(const u32x4*)(src + (size_t)idx * 4);
      *(u32x4*)&shw[wid][idx * 4] = val;
    }
  }
  __syncthreads();
  const __bf16* sh = (const __bf16*)shw[wid];
  const int k = lane & 15, g = lane >> 4;
  float sum = 0.f;
  for (int i = g; i < NF; i += 4)
    for (int j = i + 1; j < NF; ++j)
      sum += (float)sh[i * NCOL + j * 16 + k] * (float)sh[j * NCOL + i * 16 + k];
  if (lane < NF) sum += (float)sh[lane * NCOL + 320];   // linear term
#pragma unroll
  for (int off = 32; off; off >>= 1) sum += __shfl_xor(sum, off);
  if (lane == 0) out[chunk_base + bl] = sum;
}

extern "C" void kernel_launch(void* const* d_in, const int* in_sizes, int n_in,
                              void* d_out, int out_size, void* d_ws, size_t ws_size,
                              hipStream_t stream) {
  const float* x = (const float*)d_in[0];
  const float* w = (const float*)d_in[1];
  const float* v = (const float*)d_in[2];
  float* out = (float*)d_out;
  char* ws = (char*)d_ws;

  const size_t vt_bytes = (size_t)NF * NCOL * KP * 2;   // 6,881,280
  __bf16* Vt = (__bf16*)ws;
  __bf16* E2 = (__bf16*)(ws + vt_bytes);

  size_t eavail = (ws_size > vt_bytes) ? ws_size - vt_bytes : 0;
  int Bc = NB;
  while (Bc > 64 && (size_t)Bc * ROWE * 2 > eavail) Bc >>= 1;

  prep_vt<<<NF * (NF + 1), 256, 0, stream>>>(v, w, Vt);
  for (int cb = 0; cb < NB; cb += Bc) {
    int tiles = Bc / 64;
    k1_gemm<<<NF * tiles, 256, 0, stream>>>(x, Vt, E2, cb, tiles);
    k2_pair<<<Bc / 4, 256, 0, stream>>>(E2, out, cb);
  }
}

// Round 6
// 86.961 us; speedup vs baseline: 2.9507x; 1.0361x over previous
//
#include <hip/hip_runtime.h>
#include <stdint.h>

// FFM: B=4096, F=20 fields x S=500 feats, K=16.
// E2[b, i*336 + g*16 + k] = sum_s x[b,i*500+s]*v[g,i*500+s,k]  (g<20)
// E2[b, i*336 + 320]      = sum_s x[b,i*500+s]*w[i*500+s]      (linear partial)
// out[b] = sum_i E2[b,i,320] + sum_{i<j,k} E2[b,i*336+j*16+k]*E2[b,j*336+i*16+k]

#define NF 20
#define FS 500
#define TFEAT 10000
#define KD 16
#define NCOL 336        // 21 frags: 320 interaction cols + 16-col w block
#define NFRG 21
#define KP 512
#define NB 4096
#define ROWE (NF * NCOL)  // 6720

typedef __bf16 bf16x8 __attribute__((ext_vector_type(8)));
typedef __bf16 bf16x2 __attribute__((ext_vector_type(2)));
typedef float  f32x4  __attribute__((ext_vector_type(4)));
typedef unsigned int u32x4 __attribute__((ext_vector_type(4)));

typedef __attribute__((address_space(1))) const void* as1cv;
typedef __attribute__((address_space(3))) void* as3v;

__device__ inline void gload_lds16(const void* g, void* l) {
  __builtin_amdgcn_global_load_lds((as1cv)g, (as3v)l, 16, 0, 0);
}

// ---------------- prep: Vt[i][n][kk], n<336: n=g*16+k -> v[g,i*500+kk,k]; n=320 -> w; rest 0
__global__ __launch_bounds__(256) void prep_vt(const float* __restrict__ v,
                                               const float* __restrict__ w,
                                               __bf16* __restrict__ Vt) {
  const int i = blockIdx.x / (NF + 1);
  const int g = blockIdx.x % (NF + 1);
  const int t = threadIdx.x;
  if (g == NF) {  // w block: rows 320..335
    const float* wf = w + (size_t)i * FS;
    __bf16* o = Vt + ((size_t)i * NCOL + 320) * KP;
    for (int idx = t; idx < 16 * KP; idx += 256) {
      int r = idx >> 9, kk = idx & (KP - 1);
      __bf16 val = (__bf16)0.f;
      if (r == 0 && kk < FS) val = (__bf16)wf[kk];
      o[(size_t)r * KP + kk] = val;
    }
    return;
  }
  __shared__ float lv[FS * 17];
  const int k = t & 15, sb = t >> 4;
  const float* vb = v + ((size_t)g * TFEAT + (size_t)i * FS) * KD;
  for (int it = 0; it < 32; ++it) {
    int s = it * 16 + sb;
    if (s < FS) lv[s * 17 + k] = vb[(size_t)s * KD + k];
  }
  __syncthreads();
  __bf16* out = Vt + ((size_t)i * NCOL + g * 16) * KP;
  for (int r = 0; r < 16; ++r) {
    int s0 = 2 * t, s1 = 2 * t + 1;
    bf16x2 pr;
    pr[0] = (s0 < FS) ? (__bf16)lv[s0 * 17 + r] : (__bf16)0.f;
    pr[1] = (s1 < FS) ? (__bf16)lv[s1 * 17 + r] : (__bf16)0.f;
    *(bf16x2*)(out + (size_t)r * KP + 2 * t) = pr;
  }
}

// ---------------- K1: per-field GEMM. BM=64, BN=336, BK=32, 16 steps, 4 waves.
// A: reg-staged bf16 dbuf [2][64][32] (8 KB): load x->regs at top (T14), cvt+ds_write
//    after compute. XOR swizzle chunk^=(row>>1)&3 (2-way = free).
// B: bf16 via global_load_lds dbuf (43 KB), swizzled source as before.
// LDS 51.2 KB -> 3 blocks/CU (12 waves/CU). One vmcnt(0)+lgkmcnt(0)+barrier per iter.
__global__ __launch_bounds__(256, 3) void k1_gemm(
    const float* __restrict__ x, const __bf16* __restrict__ Vt,
    __bf16* __restrict__ E2, int chunk_base, int tiles) {
  __shared__ __bf16 As[2][64][32];        // 8192 B
  __shared__ __bf16 Bs[2][NCOL * 32];     // 43008 B

  const int bx = blockIdx.x;
  const int i  = bx / tiles;
  const int tb = bx % tiles;
  const int tid = threadIdx.x;
  const int lane = tid & 63, wid = tid >> 6;
  const int b0 = chunk_base + tb * 64;

  // A stage (per thread): row = tid>>2, 8 cols at (tid&3)*8; swizzled chunk
  const int arow = tid >> 2;
  const int ac8 = (tid & 3) * 8;
  const int apch = (tid & 3) ^ ((tid >> 3) & 3);   // (tid&3) ^ ((arow>>1)&3)
  const float* xrow = x + (size_t)(b0 + arow) * TFEAT + i * FS;
  // B stage: instr q covers 16 rows x 4 chunks; src chunk pre-swizzled
  const int brow_off = lane >> 2;                   // 0..15
  const int blc8 = ((lane & 3) ^ ((lane >> 3) & 3)) * 8;
  const __bf16* VtB = Vt + (size_t)i * NCOL * KP;

  f32x4 ar0, ar1;
  auto aload = [&](int t) {
    int kk = t * 32 + ac8;
    int c0 = kk > 496 ? 496 : kk;          // clamp: junk cols pair with zero B rows
    int c1 = kk + 4 > 496 ? 496 : kk + 4;
    ar0 = *(const f32x4*)(xrow + c0);
    ar1 = *(const f32x4*)(xrow + c1);
  };
  auto astore = [&](int buf) {
    bf16x8 h;
    h[0] = (__bf16)ar0[0]; h[1] = (__bf16)ar0[1];
    h[2] = (__bf16)ar0[2]; h[3] = (__bf16)ar0[3];
    h[4] = (__bf16)ar1[0]; h[5] = (__bf16)ar1[1];
    h[6] = (__bf16)ar1[2]; h[7] = (__bf16)ar1[3];
    *(bf16x8*)(&As[buf][arow][apch * 8]) = h;
  };
  auto issueB = [&](int t, int buf) {
    int soffB = t * 32 + blc8;
#pragma unroll
    for (int jj = 0; jj < 6; ++jj) {
      int q = wid + 4 * jj;
      if (q < NFRG)
        gload_lds16(VtB + (size_t)(16 * q + brow_off) * KP + soffB,
                    (void*)&Bs[buf][q * 16 * 32]);
    }
  };

  const int nfr = wid ? 5 : 6;
  const int Fbase = wid ? (1 + wid * 5) : 0;
  const int ar = lane & 15, akc = lane >> 4;

  f32x4 acc[4][6];
#pragma unroll
  for (int m = 0; m < 4; ++m)
#pragma unroll
    for (int nf = 0; nf < 6; ++nf) acc[m][nf] = (f32x4){0.f, 0.f, 0.f, 0.f};

  // prologue: A(0) regs first (oldest), then B(0) glds; astore waits only A regs
  aload(0);
  issueB(0, 0);
  astore(0);
  asm volatile("s_waitcnt vmcnt(0) lgkmcnt(0)" ::: "memory");
  __builtin_amdgcn_s_barrier();

  for (int t = 0; t < 16; ++t) {
    const int cur = t & 1;
    if (t < 15) {
      aload(t + 1);                 // global->reg, issued first (oldest in FIFO)
      issueB(t + 1, cur ^ 1);       // glds after: astore's reg-wait leaves B in flight
    }
    __builtin_amdgcn_sched_barrier(0);

    bf16x8 bfr[6];
#pragma unroll
    for (int nf = 0; nf < 6; ++nf)
      if (nf < nfr) {
        int n_ = (Fbase + nf) * 16 + ar;
        int pc = akc ^ ((n_ >> 1) & 3);
        bfr[nf] = *(const bf16x8*)&Bs[cur][n_ * 32 + pc * 8];
      }
#pragma unroll
    for (int m = 0; m < 4; ++m) {
      int row = m * 16 + ar;
      int pch = akc ^ ((row >> 1) & 3);
      bf16x8 af = *(const bf16x8*)(&As[cur][row][pch * 8]);
#pragma unroll
      for (int nf = 0; nf < 6; ++nf)
        if (nf < nfr)
          acc[m][nf] = __builtin_amdgcn_mfma_f32_16x16x32_bf16(af, bfr[nf],
                                                               acc[m][nf], 0, 0, 0);
    }
    if (t < 15) {
      astore(cur ^ 1);              // cvt+ds_write; waits own A regs (vmcnt(6))
      asm volatile("s_waitcnt vmcnt(0) lgkmcnt(0)" ::: "memory");
      __builtin_amdgcn_s_barrier();
    }
  }

  // epilogue: C/D layout col=lane&15, row=(lane>>4)*4+r
  const int lr4 = (lane >> 4) * 4, lcol = lane & 15;
#pragma unroll
  for (int m = 0; m < 4; ++m)
#pragma unroll
    for (int nf = 0; nf < 6; ++nf)
      if (nf < nfr) {
        int n = (Fbase + nf) * 16 + lcol;
#pragma unroll
        for (int r = 0; r < 4; ++r) {
          int bl = tb * 64 + m * 16 + lr4 + r;
          E2[(size_t)bl * ROWE + i * NCOL + n] = (__bf16)acc[m][nf][r];
        }
      }
}

// ---------------- K2: pair + linear reduction, 1 wave per batch row
__global__ __launch_bounds__(256) void k2_pair(
    const __bf16* __restrict__ E2, float* __restrict__ out, int chunk_base) {
  __shared__ __align__(16) unsigned shw[4][3360];  // 13440 B per wave
  const int tid = threadIdx.x, lane = tid & 63, wid = tid >> 6;
  const int bl = blockIdx.x * 4 + wid;
  const unsigned* src = (const unsigned*)(E2 + (size_t)bl * ROWE);
  for (int it = 0; it < 14; ++it) {
    int idx = it * 64 + lane;             // 16B units; 840 total
    if (idx < 840) {
      u32x4 val = *(const u32x4*)(src + (size_t)idx * 4);
      *(u32x4*)&shw[wid][idx * 4] = val;
    }
  }
  __syncthreads();
  const __bf16* sh = (const __bf16*)shw[wid];
  const int k = lane & 15, g = lane >> 4;
  float sum = 0.f;
  for (int i = g; i < NF; i += 4)
    for (int j = i + 1; j < NF; ++j)
      sum += (float)sh[i * NCOL + j * 16 + k] * (float)sh[j * NCOL + i * 16 + k];
  if (lane < NF) sum += (float)sh[lane * NCOL + 320];   // linear term
#pragma unroll
  for (int off = 32; off; off >>= 1) sum += __shfl_xor(sum, off);
  if (lane == 0) out[chunk_base + bl] = sum;
}

extern "C" void kernel_launch(void* const* d_in, const int* in_sizes, int n_in,
                              void* d_out, int out_size, void* d_ws, size_t ws_size,
                              hipStream_t stream) {
  const float* x = (const float*)d_in[0];
  const float* w = (const float*)d_in[1];
  const float* v = (const float*)d_in[2];
  float* out = (float*)d_out;
  char* ws = (char*)d_ws;

  const size_t vt_bytes = (size_t)NF * NCOL * KP * 2;   // 6,881,280
  __bf16* Vt = (__bf16*)ws;
  __bf16* E2 = (__bf16*)(ws + vt_bytes);

  size_t eavail = (ws_size > vt_bytes) ? ws_size - vt_bytes : 0;
  int Bc = NB;
  while (Bc > 64 && (size_t)Bc * ROWE * 2 > eavail) Bc >>= 1;

  prep_vt<<<NF * (NF + 1), 256, 0, stream>>>(v, w, Vt);
  for (int cb = 0; cb < NB; cb += Bc) {
    int tiles = Bc / 64;
    k1_gemm<<<NF * tiles, 256, 0, stream>>>(x, Vt, E2, cb, tiles);
    k2_pair<<<Bc / 4, 256, 0, stream>>>(E2, out, cb);
  }
}